// Round 4
// baseline (121.333 us; speedup 1.0000x reference)
//
#include <hip/hip_runtime.h>
#include <hip/hip_bf16.h>

// Problem constants (fixed by reference):
//   x[N=8][INC=32][INN=50000] fp32, A[OUTN=8192][MAXD=16] int32,
//   mask[OUTN][MAXD][1] fp32, weight[INC=32][OUTC=32] fp32, bias[OUTC=32][OUTN=8192]
//   out[N=8][OUTC=32][OUTN=8192] fp32
// K1: transpose x -> xt[INN][256] bf16 (row j = n*32+c).  K2: gather+pool+matmul fp32.
// R8 (Model-A discriminator): (1) K2 gather at 16B/lane: lane loads uint4 (8 bf16),
//     half-waves split even/odd neighbors, BOTH nodes' 16 loads (16 KB/wave) issued
//     before any consume -> 2x bytes-in-flight per CU vs R7; __shfl_xor(,32)
//     combines d-parities. (2) K1: 782 blocks, r-loop inside -> each block writes
//     complete 512B xt rows, 4x work/block. If neutral again -> overhead-bound
//     (Model B) and kernels are at their floor.

#define INN   50000
#define NR    256        // N*INC rows
#define OUTN  8192
#define MAXD  16
#define TO    32         // output nodes per block in K2

static __device__ __forceinline__ float bf2f(unsigned short u) {
    return __uint_as_float(((unsigned int)u) << 16);
}
static __device__ __forceinline__ float bf2f_lo(unsigned v) {
    return __uint_as_float(v << 16);
}
static __device__ __forceinline__ float bf2f_hi(unsigned v) {
    return __uint_as_float(v & 0xffff0000u);
}

static __device__ __forceinline__ unsigned pack2(float a, float b) {
    const unsigned lo = (unsigned)__bfloat16_as_ushort(__float2bfloat16(a));
    const unsigned hi = (unsigned)__bfloat16_as_ushort(__float2bfloat16(b));
    return lo | (hi << 16);
}

// ---------------- Kernel 1: transpose x[256][50000] -> xt_bf16[50000][256] ----
// 782 blocks x 256 thr; each block owns a 64-wide i-range and loops all 4 r-tiles,
// so every 512B xt row is written complete by ONE block (4 sequential 128B lines).
// LDS pitch 65: load-scatter and store-gather are <=2-way bank-aliased (free).
__global__ __launch_bounds__(256) void transpose_x(const float* __restrict__ x,
                                                   unsigned short* __restrict__ xt) {
    __shared__ float tile[64 * 65];
    const int t  = threadIdx.x;
    const int i0 = blockIdx.x * 64;   // column (INN) tile base

    for (int by = 0; by < 4; ++by) {
        const int r0 = by * 64;
        // ---- load: lanes sweep i (coalesced float4), 16 rows per k-step
        {
            const int i4l = t & 15;        // which float4 within the 64-wide i tile
            const int rl0 = t >> 4;        // row within tile
            const float4* x4 = (const float4*)x;
            const int i4base = (i0 >> 2) + i4l;
            const bool iv = (i4base < (INN / 4));   // INN % 4 == 0
            for (int k = 0; k < 4; ++k) {
                const int rl = rl0 + 16 * k;
                float4 v = iv ? x4[(size_t)(r0 + rl) * (INN / 4) + i4base]
                              : make_float4(0.f, 0.f, 0.f, 0.f);
                const int ib = i4l * 4;
                tile[(ib + 0) * 65 + rl] = v.x;
                tile[(ib + 1) * 65 + rl] = v.y;
                tile[(ib + 2) * 65 + rl] = v.z;
                tile[(ib + 3) * 65 + rl] = v.w;
            }
        }
        __syncthreads();
        // ---- store: lanes sweep r (coalesced 16B/lane = 8 bf16), 8 i-rows/wave
        {
            const int r8l = t & 7;         // which 8-ushort group within the 64 r
            const int il0 = t >> 3;        // 0..31
            for (int k = 0; k < 2; ++k) {
                const int il = il0 + 32 * k;
                const int i  = i0 + il;
                if (i < INN) {
                    const float* src = &tile[il * 65 + r8l * 8];
                    uint4 b;
                    b.x = pack2(src[0], src[1]);
                    b.y = pack2(src[2], src[3]);
                    b.z = pack2(src[4], src[5]);
                    b.w = pack2(src[6], src[7]);
                    *(uint4*)&xt[(size_t)i * NR + r0 + 8 * r8l] = b;
                }
            }
        }
        __syncthreads();   // tile reused next r-tile
    }
}

// ---------------- Kernel 2: gather + masked pool + 32x32 matmul + bias ------
// One block = 32 output nodes, 1024 threads (16 wave-groups x 2 nodes).
// Gather: lane l loads uint4 (16B = 8 bf16); half-wave hi=l>>5 takes neighbors
// of matching parity (d = 2*dd + hi), so each half-wave covers a full 512B row.
// Both nodes' 16 row-loads are issued before any FMA (16 KB in flight / wave).
// __shfl_xor(a,32) merges the even/odd partial sums.
__global__ __launch_bounds__(1024) void gather_gemm(const unsigned short* __restrict__ xt,
                                                    const int*   __restrict__ A,
                                                    const float* __restrict__ mask,
                                                    const float* __restrict__ W,
                                                    const float* __restrict__ bias,
                                                    float* __restrict__ out) {
    // pooled pitch 260: 16B-aligned rows; LDS ops cheap (<=8-way worst case).
    __shared__ float pooled[TO * 260];   // 33.3 KB
    __shared__ float Wt[32 * 36];        // Wt[cd][c], pitch 36 (16B aligned rows)
    __shared__ int   Ash[TO * MAXD];     // 512
    __shared__ float Msh[TO * MAXD];

    const int t  = threadIdx.x;
    const int o0 = blockIdx.x * TO;

    // stage A, mask (512 entries each), and transposed W (1024 weights)
    if (t < TO * MAXD) {
        Ash[t] = A[o0 * MAXD + t];
        Msh[t] = mask[o0 * MAXD + t];
    }
    {
        const int c = t >> 5, cd = t & 31;
        Wt[cd * 36 + c] = W[t];          // t covers all 1024 weights
    }
    __syncthreads();

    // ---- phase 1: gather
    {
        const int lo = t & 31;                 // uint4 column within row half-sweep
        const int hi = (t >> 5) & 1;           // neighbor parity for this half-wave
        const int og = t >> 6;                 // 16 wave-groups
        const uint4* xt16 = (const uint4*)xt;  // row pitch = 32 uint4
        const int ol0 = og * 2, ol1 = og * 2 + 1;

        uint4 u0[8], u1[8];
#pragma unroll
        for (int dd = 0; dd < 8; ++dd) {
            const int idx = Ash[ol0 * MAXD + 2 * dd + hi];   // 2 addrs/wave -> broadcast
            u0[dd] = xt16[(size_t)idx * 32 + lo];
        }
#pragma unroll
        for (int dd = 0; dd < 8; ++dd) {
            const int idx = Ash[ol1 * MAXD + 2 * dd + hi];
            u1[dd] = xt16[(size_t)idx * 32 + lo];
        }

        float a0[8] = {0.f,0.f,0.f,0.f,0.f,0.f,0.f,0.f};
        float a1[8] = {0.f,0.f,0.f,0.f,0.f,0.f,0.f,0.f};
#pragma unroll
        for (int dd = 0; dd < 8; ++dd) {
            const float s0 = Msh[ol0 * MAXD + 2 * dd + hi];
            a0[0] += s0 * bf2f_lo(u0[dd].x);  a0[1] += s0 * bf2f_hi(u0[dd].x);
            a0[2] += s0 * bf2f_lo(u0[dd].y);  a0[3] += s0 * bf2f_hi(u0[dd].y);
            a0[4] += s0 * bf2f_lo(u0[dd].z);  a0[5] += s0 * bf2f_hi(u0[dd].z);
            a0[6] += s0 * bf2f_lo(u0[dd].w);  a0[7] += s0 * bf2f_hi(u0[dd].w);
            const float s1 = Msh[ol1 * MAXD + 2 * dd + hi];
            a1[0] += s1 * bf2f_lo(u1[dd].x);  a1[1] += s1 * bf2f_hi(u1[dd].x);
            a1[2] += s1 * bf2f_lo(u1[dd].y);  a1[3] += s1 * bf2f_hi(u1[dd].y);
            a1[4] += s1 * bf2f_lo(u1[dd].z);  a1[5] += s1 * bf2f_hi(u1[dd].z);
            a1[6] += s1 * bf2f_lo(u1[dd].w);  a1[7] += s1 * bf2f_hi(u1[dd].w);
        }
        // merge even/odd-parity partial sums across the 32-lane halves
#pragma unroll
        for (int j = 0; j < 8; ++j) {
            a0[j] += __shfl_xor(a0[j], 32, 64);
            a1[j] += __shfl_xor(a1[j], 32, 64);
        }
        // lane covers r = lo*8 + 4*hi .. +3 (static indexing only; rule #20)
        const float4 w0 = hi ? make_float4(a0[4], a0[5], a0[6], a0[7])
                             : make_float4(a0[0], a0[1], a0[2], a0[3]);
        const float4 w1 = hi ? make_float4(a1[4], a1[5], a1[6], a1[7])
                             : make_float4(a1[0], a1[1], a1[2], a1[3]);
        *(float4*)&pooled[ol0 * 260 + lo * 8 + 4 * hi] = w0;
        *(float4*)&pooled[ol1 * 260 + lo * 8 + 4 * hi] = w1;
    }
    __syncthreads();

    // ---- phase 2 (t<256 only): thread = (n, cd). 32-term dot per node,
    // each lane writes a full 128B run of out. Idling waves 4..15 here is free.
    if (t < 256) {
        const int n  = t >> 5;   // 0..7
        const int cd = t & 31;   // 0..31
        float4 w[8];
#pragma unroll
        for (int cc = 0; cc < 8; ++cc)
            w[cc] = *(const float4*)&Wt[cd * 36 + 4 * cc];

        float res[TO];
#pragma unroll
        for (int ol = 0; ol < TO; ++ol) {
            const float4* pr = (const float4*)&pooled[ol * 260 + n * 32];
            float s = 0.f;
#pragma unroll
            for (int cc = 0; cc < 8; ++cc) {
                const float4 p = pr[cc];       // few addrs/wave -> LDS broadcast
                s += p.x * w[cc].x + p.y * w[cc].y + p.z * w[cc].z + p.w * w[cc].w;
            }
            res[ol] = s;
        }

        const size_t obase = (size_t)n * (32 * OUTN) + (size_t)cd * OUTN + o0;
        const size_t bbase = (size_t)cd * OUTN + o0;
#pragma unroll
        for (int q = 0; q < 8; ++q) {
            const float4 b = *(const float4*)&bias[bbase + 4 * q];
            float4 r;
            r.x = res[4 * q + 0] + b.x;
            r.y = res[4 * q + 1] + b.y;
            r.z = res[4 * q + 2] + b.z;
            r.w = res[4 * q + 3] + b.w;
            *(float4*)&out[obase + 4 * q] = r;
        }
    }
}

extern "C" void kernel_launch(void* const* d_in, const int* in_sizes, int n_in,
                              void* d_out, int out_size, void* d_ws, size_t ws_size,
                              hipStream_t stream) {
    const float* x    = (const float*)d_in[0];
    const int*   A    = (const int*)  d_in[1];
    const float* mask = (const float*)d_in[2];
    const float* W    = (const float*)d_in[3];
    const float* bias = (const float*)d_in[4];
    float* out = (float*)d_out;
    unsigned short* xt = (unsigned short*)d_ws;   // 50000*256*2 = 25.6 MB scratch

    // K1: 782 i-tiles (ceil(50000/64)), all 4 r-tiles per block
    transpose_x<<<782, 256, 0, stream>>>(x, xt);
    // K2: 8192/32 = 256 blocks x 1024 threads, 2 nodes per wave-group
    gather_gemm<<<OUTN / TO, 1024, 0, stream>>>(xt, A, mask, W, bias, out);
}